// Round 3
// baseline (434.455 us; speedup 1.0000x reference)
//
#include <hip/hip_runtime.h>
#include <cstddef>

#define BB 4096
#define DIN 2048
#define RR 7
#define DP 128
#define KK 25
#define DC 16
#define NITERS 3
#define RKH (RR*KK*DC)   // 2800
#define RK  (RR*KK)      // 175
#define KH  (KK*DC)      // 400
#define HD  (RR*DC)      // 112
#define H4  (4*HD)       // 448

typedef __attribute__((ext_vector_type(8))) short bf16x8;
typedef __attribute__((ext_vector_type(4))) float f32x4;

__device__ __forceinline__ unsigned pk_bf16(float a, float b) {
    union { float f; unsigned u; } xa, xb;
    xa.f = a; xb.f = b;
    unsigned ua = (xa.u + 0x7FFFu + ((xa.u >> 16) & 1u)) >> 16;
    unsigned ub = (xb.u + 0x7FFFu + ((xb.u >> 16) & 1u)) >> 16;
    return (ua & 0xFFFFu) | (ub << 16);
}

__device__ __forceinline__ float gelu_tanh(float x) {
    float x2 = x * x;
    float tt = x * (0.7978845608f + 0.03567740814f * x2);
    float e = __expf(2.0f * tt);
    float th = 1.0f - 2.0f / (e + 1.0f);
    return 0.5f * x * (1.0f + th);
}

// ---------------------------------------------------------------------------
// Prep: transpose fp32 [RS][CS] -> bf16 [CS][RSpad] (rows >= RS zero-padded).
// grid (ceil(RSpad/64), ceil(CS/64), batch)
// ---------------------------------------------------------------------------
__global__ __launch_bounds__(256) void transpose_cvt_kernel(
    const float* __restrict__ src, unsigned short* __restrict__ dst,
    int RS, int RSpad, int CS)
{
    __shared__ float T[64][65];
    int r0 = blockIdx.x * 64, c0 = blockIdx.y * 64;
    src += (size_t)blockIdx.z * RS * CS;
    dst += (size_t)blockIdx.z * RSpad * CS;
    int t = threadIdx.x;
    for (int s = t; s < 64 * 16; s += 256) {
        int row = s >> 4, c4 = s & 15;
        int gr = r0 + row, gc = c0 + c4 * 4;
        float4 v = make_float4(0.f, 0.f, 0.f, 0.f);
        if (gr < RS && gc < CS) v = *(const float4*)(src + (size_t)gr * CS + gc);
        T[row][c4 * 4 + 0] = v.x; T[row][c4 * 4 + 1] = v.y;
        T[row][c4 * 4 + 2] = v.z; T[row][c4 * 4 + 3] = v.w;
    }
    __syncthreads();
    for (int s = t; s < 64 * 16; s += 256) {
        int col = s >> 4, r4 = s & 15;
        int gc = c0 + col, gr = r0 + r4 * 4;
        if (gc < CS && gr + 3 < RSpad) {
            unsigned lo = pk_bf16(T[r4 * 4 + 0][col], T[r4 * 4 + 1][col]);
            unsigned hi = pk_bf16(T[r4 * 4 + 2][col], T[r4 * 4 + 3][col]);
            *(uint2*)(dst + (size_t)gc * RSpad + gr) = make_uint2(lo, hi);
        }
    }
}

// ---------------------------------------------------------------------------
// Prep for act: Wg[i][r] = g[i]*Wa[i][r]; GC[r] = sum_i g_i*Wa_ir; GC[7+r] = sum_i b_i*Wa_ir
// single block
// ---------------------------------------------------------------------------
__global__ __launch_bounds__(256) void prep_act_kernel(
    const float* __restrict__ g, const float* __restrict__ bvec,
    const float* __restrict__ Wa, float* __restrict__ Wg, float* __restrict__ GC)
{
    __shared__ float red[4];
    int t = threadIdx.x, w = t >> 6, l = t & 63;
    float Gp[RR], Cp[RR];
#pragma unroll
    for (int r = 0; r < RR; ++r) { Gp[r] = 0.f; Cp[r] = 0.f; }
    for (int i = t; i < DIN; i += 256) {
        float gi = g[i], bi = bvec[i];
#pragma unroll
        for (int r = 0; r < RR; ++r) {
            float wv = Wa[i * RR + r];
            Wg[i * RR + r] = gi * wv;
            Gp[r] += gi * wv;
            Cp[r] += bi * wv;
        }
    }
    for (int which = 0; which < 2; ++which) {
#pragma unroll
        for (int r = 0; r < RR; ++r) {
            float v = which ? Cp[r] : Gp[r];
            for (int off = 32; off; off >>= 1) v += __shfl_down(v, off);
            if (l == 0) red[w] = v;
            __syncthreads();
            if (t == 0) GC[which * RR + r] = red[0] + red[1] + red[2] + red[3];
            __syncthreads();
        }
    }
}

// ---------------------------------------------------------------------------
// act v2: single pass. acc_r = rstd*(dot_r - m*G_r) + C_r + ba_r; sigmoid+clip.
// grid 512, 8 rows/block (2 per wave).
// ---------------------------------------------------------------------------
__global__ __launch_bounds__(256) void act_v2(
    const float* __restrict__ z, const float* __restrict__ Wg,
    const float* __restrict__ GC, const float* __restrict__ ba,
    float* __restrict__ act_out)
{
    __shared__ float WgS[DIN * RR];
    __shared__ float GCs[2 * RR];
    int t = threadIdx.x, w = t >> 6, l = t & 63;
    for (int s = t; s < DIN * RR; s += 256) WgS[s] = Wg[s];
    if (t < 2 * RR) GCs[t] = GC[t];
    __syncthreads();
    for (int rr = 0; rr < 2; ++rr) {
        int row = blockIdx.x * 8 + w * 2 + rr;
        const float* zr = z + (size_t)row * DIN;
        float s1 = 0.f, s2 = 0.f, d[RR];
#pragma unroll
        for (int r = 0; r < RR; ++r) d[r] = 0.f;
        for (int q = 0; q < DIN / 64; ++q) {
            int i = l + 64 * q;
            float v = zr[i];
            s1 += v; s2 += v * v;
#pragma unroll
            for (int r = 0; r < RR; ++r) d[r] += v * WgS[i * RR + r];
        }
        for (int off = 1; off < 64; off <<= 1) {
            s1 += __shfl_xor(s1, off); s2 += __shfl_xor(s2, off);
#pragma unroll
            for (int r = 0; r < RR; ++r) d[r] += __shfl_xor(d[r], off);
        }
        float m = s1 * (1.0f / DIN);
        float var = s2 * (1.0f / DIN) - m * m;
        float rs = rsqrtf(var + 1e-5f);
        if (l < RR) {
            float v = rs * (d[l] - m * GCs[l]) + GCs[RR + l] + ba[l];
            float sg = 1.0f / (1.0f + expf(-v));
            act_out[(size_t)row * RR + l] = fminf(fmaxf(sg, 0.0f), 1.0f);
        }
    }
}

// ---------------------------------------------------------------------------
// pose v2 (MFMA): 64x128 tile, BK=64. grid (64, 7).
// ---------------------------------------------------------------------------
__global__ __launch_bounds__(256) void pose64(
    const float* __restrict__ z, const unsigned short* __restrict__ WpT,
    const float* __restrict__ bp, float* __restrict__ pose_out)
{
    __shared__ __align__(16) unsigned short As[64 * 72];
    __shared__ __align__(16) unsigned short Bs[128 * 72];
    __shared__ float sq[2][64];
    int m0 = blockIdx.x * 64, r = blockIdx.y, n0 = r * DP;
    int t = threadIdx.x, w = t >> 6, l = t & 63;
    int lrow = l & 15, koff = l >> 4;
    int rhalf = w >> 1, chalf = w & 1;
    f32x4 acc[2][4];
#pragma unroll
    for (int i = 0; i < 2; ++i)
#pragma unroll
        for (int j = 0; j < 4; ++j) acc[i][j] = 0.0f;
    for (int kt = 0; kt < DIN; kt += 64) {
#pragma unroll
        for (int q = 0; q < 2; ++q) {
            int s = t + 256 * q;           // 512 slots of 8 elems
            int row = s >> 3, e8 = s & 7;
            const float* p = z + (size_t)(m0 + row) * DIN + kt + e8 * 8;
            float4 v0 = *(const float4*)p;
            float4 v1 = *(const float4*)(p + 4);
            *(uint4*)(As + row * 72 + e8 * 8) =
                make_uint4(pk_bf16(v0.x, v0.y), pk_bf16(v0.z, v0.w),
                           pk_bf16(v1.x, v1.y), pk_bf16(v1.z, v1.w));
        }
#pragma unroll
        for (int q = 0; q < 4; ++q) {
            int s = t + 256 * q;           // 1024 slots
            int col = s >> 3, e8 = s & 7;
            uint4 v = *(const uint4*)(WpT + (size_t)(n0 + col) * DIN + kt + e8 * 8);
            *(uint4*)(Bs + col * 72 + e8 * 8) = v;
        }
        __syncthreads();
#pragma unroll
        for (int ks = 0; ks < 2; ++ks) {
            bf16x8 a[2], b[4];
#pragma unroll
            for (int i = 0; i < 2; ++i)
                a[i] = *(const bf16x8*)(As + (rhalf * 32 + i * 16 + lrow) * 72 + ks * 32 + koff * 8);
#pragma unroll
            for (int j = 0; j < 4; ++j)
                b[j] = *(const bf16x8*)(Bs + (chalf * 64 + j * 16 + lrow) * 72 + ks * 32 + koff * 8);
#pragma unroll
            for (int i = 0; i < 2; ++i)
#pragma unroll
                for (int j = 0; j < 4; ++j)
                    acc[i][j] = __builtin_amdgcn_mfma_f32_16x16x32_bf16(a[i], b[j], acc[i][j], 0, 0, 0);
        }
        __syncthreads();
    }
    float bpv[4];
#pragma unroll
    for (int j = 0; j < 4; ++j) bpv[j] = bp[n0 + chalf * 64 + j * 16 + lrow];
    float ns_[2][4];
#pragma unroll
    for (int i = 0; i < 2; ++i)
#pragma unroll
        for (int reg = 0; reg < 4; ++reg) {
            float ss = 0.f;
#pragma unroll
            for (int j = 0; j < 4; ++j) {
                float x = acc[i][j][reg] + bpv[j];
                acc[i][j][reg] = x;
                ss += x * x;
            }
            ss += __shfl_xor(ss, 1); ss += __shfl_xor(ss, 2);
            ss += __shfl_xor(ss, 4); ss += __shfl_xor(ss, 8);
            ns_[i][reg] = ss;
        }
    if (lrow == 0) {
#pragma unroll
        for (int i = 0; i < 2; ++i)
#pragma unroll
            for (int reg = 0; reg < 4; ++reg)
                sq[chalf][rhalf * 32 + i * 16 + koff * 4 + reg] = ns_[i][reg];
    }
    __syncthreads();
#pragma unroll
    for (int i = 0; i < 2; ++i)
#pragma unroll
        for (int reg = 0; reg < 4; ++reg) {
            int rl = rhalf * 32 + i * 16 + koff * 4 + reg;
            float ns = sq[0][rl] + sq[1][rl];
            float factor = (ns / fmaxf(1.0f + ns, 1e-6f)) / (sqrtf(ns) + 1e-6f);
            size_t rowbase = ((size_t)(m0 + rl) * RR + r) * DP;
#pragma unroll
            for (int j = 0; j < 4; ++j)
                pose_out[rowbase + chalf * 64 + j * 16 + lrow] = acc[i][j][reg] * factor;
        }
}

// ---------------------------------------------------------------------------
// Kernel 3 (MFMA): votes — unchanged from R2.
// ---------------------------------------------------------------------------
__global__ __launch_bounds__(256) void votes_mfma(
    const float* __restrict__ pose, const unsigned short* __restrict__ wcT,
    float* __restrict__ u_out)
{
    __shared__ __align__(16) unsigned short As[128 * 152];
    __shared__ __align__(16) unsigned short Bs[80 * 152];
    int m0 = blockIdx.x * 128, r = blockIdx.y, n0 = blockIdx.z * 80;
    int t = threadIdx.x;
    int w = t >> 6, l = t & 63;
    int lrow = l & 15, koff = l >> 4;
    int rbase = w * 32;
#pragma unroll
    for (int q = 0; q < 16; ++q) {
        int s = t + 256 * q;
        int row = s >> 5, k4 = s & 31;
        float4 v = *(const float4*)(pose + ((size_t)(m0 + row) * RR + r) * DP + k4 * 4);
        *(uint2*)(As + row * 152 + k4 * 4) = make_uint2(pk_bf16(v.x, v.y), pk_bf16(v.z, v.w));
    }
    const unsigned short* wr_ = wcT + (size_t)r * KH * DP;
#pragma unroll
    for (int q = 0; q < 5; ++q) {
        int s = t + 256 * q;
        int col = s >> 4, k8 = s & 15;
        uint4 v = *(const uint4*)(wr_ + (size_t)(n0 + col) * DP + k8 * 8);
        *(uint4*)(Bs + col * 152 + k8 * 8) = v;
    }
    __syncthreads();
    f32x4 acc[2][5];
#pragma unroll
    for (int i = 0; i < 2; ++i)
#pragma unroll
        for (int j = 0; j < 5; ++j) acc[i][j] = 0.0f;
#pragma unroll
    for (int ks = 0; ks < 4; ++ks) {
        bf16x8 a[2], b[5];
#pragma unroll
        for (int i = 0; i < 2; ++i)
            a[i] = *(const bf16x8*)(As + (rbase + i * 16 + lrow) * 152 + ks * 32 + koff * 8);
#pragma unroll
        for (int j = 0; j < 5; ++j)
            b[j] = *(const bf16x8*)(Bs + (j * 16 + lrow) * 152 + ks * 32 + koff * 8);
#pragma unroll
        for (int i = 0; i < 2; ++i)
#pragma unroll
            for (int j = 0; j < 5; ++j)
                acc[i][j] = __builtin_amdgcn_mfma_f32_16x16x32_bf16(a[i], b[j], acc[i][j], 0, 0, 0);
    }
#pragma unroll
    for (int i = 0; i < 2; ++i)
#pragma unroll
        for (int reg = 0; reg < 4; ++reg) {
            int row = m0 + rbase + i * 16 + koff * 4 + reg;
            size_t base = ((size_t)row * RR + r) * KH + n0;
#pragma unroll
            for (int j = 0; j < 5; ++j)
                u_out[base + j * 16 + lrow] = acc[i][j][reg];
        }
}

// ---------------------------------------------------------------------------
// Kernel 4: routing — one wave per b; optional per-(b,k) LN stats for head.
// ---------------------------------------------------------------------------
__global__ __launch_bounds__(64) void routing_kernel(
    const float* __restrict__ u_in, const float* __restrict__ act_in,
    const float* __restrict__ lncg, const float* __restrict__ lncb,
    const float* __restrict__ beta_u,
    float* __restrict__ q_out, float* __restrict__ cp_out,
    float* __restrict__ ca_out, float* __restrict__ rce_out,
    float* __restrict__ ce_out, float2* __restrict__ stats)
{
    __shared__ __align__(16) float U[RKH];
    __shared__ float Q[RK];
    __shared__ float CP[KH];
    __shared__ float AG[RK];
    __shared__ float A7[RR];
    int b = blockIdx.x, t = threadIdx.x;
    const float4* u4 = (const float4*)(u_in + (size_t)b * RKH);
    float4* U4 = (float4*)U;
    for (int p = t; p < RKH / 4; p += 64) U4[p] = u4[p];
    if (t < RR) A7[t] = act_in[(size_t)b * RR + t];
    for (int p = t; p < RK; p += 64) Q[p] = 1.0f / KK;
    __syncthreads();
    for (int it = 0; it < NITERS; ++it) {
        for (int p = t; p < KH; p += 64) {
            int k = p / DC;
            float s = 0.f;
#pragma unroll
            for (int r = 0; r < RR; ++r) s += Q[r * KK + k] * A7[r] * U[r * KH + p];
            CP[p] = s;
        }
        __syncthreads();
        if (t < KK) {
            float m = 0.f;
#pragma unroll
            for (int h = 0; h < DC; ++h) m += CP[t * DC + h];
            m *= (1.0f / DC);
            float v = 0.f;
#pragma unroll
            for (int h = 0; h < DC; ++h) { float d = CP[t * DC + h] - m; v += d * d; }
            v *= (1.0f / DC);
            float rstd = rsqrtf(v + 1e-5f);
#pragma unroll
            for (int h = 0; h < DC; ++h)
                CP[t * DC + h] = (CP[t * DC + h] - m) * rstd * lncg[h] + lncb[h];
        }
        __syncthreads();
        for (int p = t; p < RK; p += 64) {
            int r = p / KK, k = p % KK;
            float s = 0.f;
#pragma unroll
            for (int h = 0; h < DC; ++h) s += CP[k * DC + h] * U[r * KH + k * DC + h];
            AG[p] = s * 0.25f;
        }
        __syncthreads();
        if (t < RR) {
            float mx = -1e30f;
            for (int k = 0; k < KK; ++k) mx = fmaxf(mx, AG[t * KK + k]);
            float e[KK], sum = 0.f;
            for (int k = 0; k < KK; ++k) { e[k] = expf(AG[t * KK + k] - mx); sum += e[k]; }
            float inv = 1.0f / sum;
            for (int k = 0; k < KK; ++k) Q[t * KK + k] = e[k] * inv;
        }
        __syncthreads();
    }
    if (t < KK) {
        float s = 0.f;
#pragma unroll
        for (int r = 0; r < RR; ++r) s += Q[r * KK + t] * A7[r];
        ca_out[(size_t)b * KK + t] = 1.0f / (1.0f + expf(-(beta_u[t] + s)));
    }
    for (int p = t; p < RK; p += 64) q_out[(size_t)b * RK + p] = Q[p];
    for (int p = t; p < KH; p += 64) cp_out[(size_t)b * KH + p] = CP[p];
    if (stats && t < 2 * KK) {
        int k = t >> 1, s = t & 1;
        float s1 = 0.f, s2 = 0.f;
#pragma unroll
        for (int r = 0; r < RR; ++r) {
            float qv = Q[r * KK + k];
#pragma unroll
            for (int j = 0; j < 8; ++j) {
                float v = qv * U[r * KH + k * DC + s * 8 + j];
                s1 += v; s2 += v * v;
            }
        }
        s1 += __shfl_xor(s1, 1); s2 += __shfl_xor(s2, 1);
        if (s == 0) {
            float m = s1 * (1.0f / HD);
            float var = s2 * (1.0f / HD) - m * m;
            stats[(size_t)b * KK + k] = make_float2(m, rsqrtf(var + 1e-5f));
        }
    }
    float4* rce4 = (float4*)(rce_out + (size_t)b * RKH);
    float4* ce4  = (float4*)ce_out;
    for (int p4 = t; p4 < RKH / 4; p4 += 64) {
        int base = p4 * 4;
        int r  = base / KH;
        int k  = (base % KH) / DC;
        int h0 = base % DC;
        float qv = Q[r * KK + k];
        float4 uv = U4[p4];
        float4 rv = make_float4(qv * uv.x, qv * uv.y, qv * uv.z, qv * uv.w);
        rce4[p4] = rv;
        size_t ci = ((size_t)b * RKH + (size_t)k * HD + (size_t)r * DC + h0) >> 2;
        ce4[ci] = rv;
    }
}

// ---------------------------------------------------------------------------
// head v3 (MFMA): A-frags from global ce + stats (LN in regs), Bs-only LDS.
// grid 800 blocks, 128 rows/block, 32 rows/wave.
// ---------------------------------------------------------------------------
__global__ __launch_bounds__(256) void head_v3(
    const float* __restrict__ ce, const float2* __restrict__ stats,
    const float* __restrict__ g, const float* __restrict__ bb,
    const unsigned short* __restrict__ W1Tp, const float* __restrict__ b1,
    const float* __restrict__ W2, const float* __restrict__ b2,
    float* __restrict__ logits)
{
    __shared__ __align__(16) unsigned short Bs[64 * 136];
    __shared__ float gbuf[HD], bbuf[HD];
    int row0 = blockIdx.x * 128;
    int t = threadIdx.x, w = t >> 6, l = t & 63;
    int lrow = l & 15, koff = l >> 4;
    int rbase = w * 32;
    if (t < HD) { gbuf[t] = g[t]; bbuf[t] = bb[t]; }
    __syncthreads();
    // A fragments: LN applied in registers, kept for all 7 N-chunks
    bf16x8 afrag[2][4];
#pragma unroll
    for (int i = 0; i < 2; ++i) {
        int row = row0 + rbase + i * 16 + lrow;
        float2 st = stats[row];
        float m = st.x, rs = st.y;
        const float* cr = ce + (size_t)row * HD;
#pragma unroll
        for (int ks = 0; ks < 4; ++ks) {
            int k = ks * 32 + koff * 8;
            union { bf16x8 v; uint4 u; } fr;
            if (k < HD) {
                float4 a0 = *(const float4*)(cr + k);
                float4 a1 = *(const float4*)(cr + k + 4);
                float y0 = (a0.x - m) * rs * gbuf[k]     + bbuf[k];
                float y1 = (a0.y - m) * rs * gbuf[k + 1] + bbuf[k + 1];
                float y2 = (a0.z - m) * rs * gbuf[k + 2] + bbuf[k + 2];
                float y3 = (a0.w - m) * rs * gbuf[k + 3] + bbuf[k + 3];
                float y4 = (a1.x - m) * rs * gbuf[k + 4] + bbuf[k + 4];
                float y5 = (a1.y - m) * rs * gbuf[k + 5] + bbuf[k + 5];
                float y6 = (a1.z - m) * rs * gbuf[k + 6] + bbuf[k + 6];
                float y7 = (a1.w - m) * rs * gbuf[k + 7] + bbuf[k + 7];
                fr.u = make_uint4(pk_bf16(y0, y1), pk_bf16(y2, y3),
                                  pk_bf16(y4, y5), pk_bf16(y6, y7));
            } else {
                fr.u = make_uint4(0, 0, 0, 0);
            }
            afrag[i][ks] = fr.v;
        }
    }
    float logitAcc[2][4];
#pragma unroll
    for (int i = 0; i < 2; ++i)
#pragma unroll
        for (int reg = 0; reg < 4; ++reg) logitAcc[i][reg] = 0.f;
    for (int nc = 0; nc < 7; ++nc) {
        __syncthreads();
#pragma unroll
        for (int q = 0; q < 4; ++q) {
            int s = t + 256 * q;               // 1024 uint4 slots
            int col = s >> 4, k8 = s & 15;
            uint4 v = *(const uint4*)(W1Tp + (size_t)(nc * 64 + col) * 128 + k8 * 8);
            *(uint4*)(Bs + col * 136 + k8 * 8) = v;
        }
        __syncthreads();
        f32x4 acc[2][4];
#pragma unroll
        for (int i = 0; i < 2; ++i)
#pragma unroll
            for (int j = 0; j < 4; ++j) acc[i][j] = 0.0f;
#pragma unroll
        for (int ks = 0; ks < 4; ++ks) {
            bf16x8 b[4];
#pragma unroll
            for (int j = 0; j < 4; ++j)
                b[j] = *(const bf16x8*)(Bs + (j * 16 + lrow) * 136 + ks * 32 + koff * 8);
#pragma unroll
            for (int i = 0; i < 2; ++i)
#pragma unroll
                for (int j = 0; j < 4; ++j)
                    acc[i][j] = __builtin_amdgcn_mfma_f32_16x16x32_bf16(afrag[i][ks], b[j], acc[i][j], 0, 0, 0);
        }
        float b1v[4], w2v[4];
#pragma unroll
        for (int j = 0; j < 4; ++j) {
            b1v[j] = b1[nc * 64 + j * 16 + lrow];
            w2v[j] = W2[nc * 64 + j * 16 + lrow];
        }
#pragma unroll
        for (int i = 0; i < 2; ++i)
#pragma unroll
            for (int reg = 0; reg < 4; ++reg) {
                float sum = 0.f;
#pragma unroll
                for (int j = 0; j < 4; ++j) {
                    float x = acc[i][j][reg] + b1v[j];
                    sum += gelu_tanh(x) * w2v[j];
                }
                logitAcc[i][reg] += sum;
            }
    }
#pragma unroll
    for (int i = 0; i < 2; ++i)
#pragma unroll
        for (int reg = 0; reg < 4; ++reg) {
            float v = logitAcc[i][reg];
            v += __shfl_xor(v, 1); v += __shfl_xor(v, 2);
            v += __shfl_xor(v, 4); v += __shfl_xor(v, 8);
            logitAcc[i][reg] = v;
        }
    if (lrow == 0) {
        float b2v = b2[0];
#pragma unroll
        for (int i = 0; i < 2; ++i)
#pragma unroll
            for (int reg = 0; reg < 4; ++reg)
                logits[row0 + rbase + i * 16 + koff * 4 + reg] = logitAcc[i][reg] + b2v;
    }
}

// ---------------------------------------------------------------------------
// head v2 (R2 fallback): LN in LDS from fp32 ce, W1T [448][112].
// ---------------------------------------------------------------------------
__global__ __launch_bounds__(256) void head_mfma(
    const float* __restrict__ ce, const float* __restrict__ g, const float* __restrict__ bb,
    const unsigned short* __restrict__ W1T, const float* __restrict__ b1,
    const float* __restrict__ W2, const float* __restrict__ b2,
    float* __restrict__ logits)
{
    __shared__ __align__(16) unsigned short As[128 * 152];
    __shared__ __align__(16) char pool[64 * 116 * 4];
    __shared__ float gbuf[HD], bbuf[HD];
    float* scr = (float*)pool;
    unsigned short* Bs = (unsigned short*)pool;
    unsigned* As32 = (unsigned*)As;
    unsigned* Bs32 = (unsigned*)Bs;
    int row0 = blockIdx.x * 128;
    int t = threadIdx.x;
    int w = t >> 6, l = t & 63;
    int lrow = l & 15, koff = l >> 4;
    if (t < HD) { gbuf[t] = g[t]; bbuf[t] = bb[t]; }
    for (int p = 0; p < 2; ++p) {
        for (int s = t; s < 64 * 28; s += 256) {
            int row = s / 28, q4 = s % 28;
            float4 v = *(const float4*)(ce + (size_t)(row0 + p * 64 + row) * HD + q4 * 4);
            *(float4*)(scr + row * 116 + q4 * 4) = v;
        }
        __syncthreads();
        {
            int tq = t & 3, row = t >> 2;
            float s1 = 0.f, s2 = 0.f;
            const float* rp = scr + row * 116 + tq * 28;
            for (int q = 0; q < 28; ++q) { float v = rp[q]; s1 += v; s2 += v * v; }
            s1 += __shfl_xor(s1, 1); s2 += __shfl_xor(s2, 1);
            s1 += __shfl_xor(s1, 2); s2 += __shfl_xor(s2, 2);
            float mean = s1 * (1.0f / HD);
            float var  = s2 * (1.0f / HD) - mean * mean;
            float rstd = rsqrtf(var + 1e-5f);
            int grow = p * 64 + row;
            for (int j = 0; j < 14; ++j) {
                int k = tq * 28 + 2 * j;
                float a = (rp[2 * j]     - mean) * rstd * gbuf[k]     + bbuf[k];
                float bv = (rp[2 * j + 1] - mean) * rstd * gbuf[k + 1] + bbuf[k + 1];
                As32[grow * 76 + tq * 14 + j] = pk_bf16(a, bv);
            }
        }
        __syncthreads();
    }
    for (int s = t; s < 128 * 8; s += 256) { int row = s >> 3; As32[row * 76 + 56 + (s & 7)] = 0; }
    for (int s = t; s < 64 * 8;  s += 256) { int col = s >> 3; Bs32[col * 76 + 56 + (s & 7)] = 0; }
    int rbase = w * 32;
    float logitAcc[2][4];
#pragma unroll
    for (int i = 0; i < 2; ++i)
#pragma unroll
        for (int reg = 0; reg < 4; ++reg) logitAcc[i][reg] = 0.f;
    for (int nc = 0; nc < 7; ++nc) {
        __syncthreads();
        for (int s = t; s < 64 * 14; s += 256) {
            int col = s / 14, k4 = s % 14;
            uint4 v = *(const uint4*)(W1T + (size_t)(nc * 64 + col) * HD + k4 * 8);
            *(uint4*)(Bs + col * 152 + k4 * 8) = v;
        }
        __syncthreads();
        f32x4 acc[2][4];
#pragma unroll
        for (int i = 0; i < 2; ++i)
#pragma unroll
            for (int j = 0; j < 4; ++j) acc[i][j] = 0.0f;
#pragma unroll
        for (int ks = 0; ks < 4; ++ks) {
            bf16x8 a[2], b[4];
#pragma unroll
            for (int i = 0; i < 2; ++i)
                a[i] = *(const bf16x8*)(As + (rbase + i * 16 + lrow) * 152 + ks * 32 + koff * 8);
#pragma unroll
            for (int j = 0; j < 4; ++j)
                b[j] = *(const bf16x8*)(Bs + (j * 16 + lrow) * 152 + ks * 32 + koff * 8);
#pragma unroll
            for (int i = 0; i < 2; ++i)
#pragma unroll
                for (int j = 0; j < 4; ++j)
                    acc[i][j] = __builtin_amdgcn_mfma_f32_16x16x32_bf16(a[i], b[j], acc[i][j], 0, 0, 0);
        }
        float b1v[4], w2v[4];
#pragma unroll
        for (int j = 0; j < 4; ++j) {
            b1v[j] = b1[nc * 64 + j * 16 + lrow];
            w2v[j] = W2[nc * 64 + j * 16 + lrow];
        }
#pragma unroll
        for (int i = 0; i < 2; ++i)
#pragma unroll
            for (int reg = 0; reg < 4; ++reg) {
                float sum = 0.f;
#pragma unroll
                for (int j = 0; j < 4; ++j) {
                    float x = acc[i][j][reg] + b1v[j];
                    sum += gelu_tanh(x) * w2v[j];
                }
                logitAcc[i][reg] += sum;
            }
    }
#pragma unroll
    for (int i = 0; i < 2; ++i)
#pragma unroll
        for (int reg = 0; reg < 4; ++reg) {
            float v = logitAcc[i][reg];
            v += __shfl_xor(v, 1); v += __shfl_xor(v, 2);
            v += __shfl_xor(v, 4); v += __shfl_xor(v, 8);
            logitAcc[i][reg] = v;
        }
    if (lrow == 0) {
        float b2v = b2[0];
#pragma unroll
        for (int i = 0; i < 2; ++i)
#pragma unroll
            for (int reg = 0; reg < 4; ++reg)
                logits[row0 + rbase + i * 16 + koff * 4 + reg] = logitAcc[i][reg] + b2v;
    }
}

// ===========================================================================
// fp32 ultimate fallback kernels (round-1)
// ===========================================================================
__global__ __launch_bounds__(256) void act_kernel(
    const float* __restrict__ z, const float* __restrict__ g, const float* __restrict__ bb,
    const float* __restrict__ Wa, const float* __restrict__ ba,
    float* __restrict__ act_out)
{
    int b = blockIdx.x;
    int t = threadIdx.x;
    __shared__ float zs[DIN];
    __shared__ float ws1[4], ws2[4];
    __shared__ float wr[4][RR];
    const float* zr = z + (size_t)b * DIN;
    float s = 0.f, s2 = 0.f;
    for (int i = t; i < DIN; i += 256) {
        float v = zr[i]; zs[i] = v; s += v; s2 += v * v;
    }
    for (int off = 32; off; off >>= 1) { s += __shfl_down(s, off); s2 += __shfl_down(s2, off); }
    int w = t >> 6, lane = t & 63;
    if (lane == 0) { ws1[w] = s; ws2[w] = s2; }
    __syncthreads();
    s  = ws1[0] + ws1[1] + ws1[2] + ws1[3];
    s2 = ws2[0] + ws2[1] + ws2[2] + ws2[3];
    float mean = s * (1.0f / DIN);
    float var  = s2 * (1.0f / DIN) - mean * mean;
    float rstd = rsqrtf(var + 1e-5f);
    float acc[RR];
#pragma unroll
    for (int r = 0; r < RR; ++r) acc[r] = 0.f;
    for (int i = t; i < DIN; i += 256) {
        float y = (zs[i] - mean) * rstd * g[i] + bb[i];
#pragma unroll
        for (int r = 0; r < RR; ++r) acc[r] += y * Wa[i * RR + r];
    }
    for (int off = 32; off; off >>= 1) {
#pragma unroll
        for (int r = 0; r < RR; ++r) acc[r] += __shfl_down(acc[r], off);
    }
    if (lane == 0) {
#pragma unroll
        for (int r = 0; r < RR; ++r) wr[w][r] = acc[r];
    }
    __syncthreads();
    if (t < RR) {
        float v = wr[0][t] + wr[1][t] + wr[2][t] + wr[3][t] + ba[t];
        float sg = 1.0f / (1.0f + expf(-v));
        sg = fminf(fmaxf(sg, 0.0f), 1.0f);
        act_out[(size_t)b * RR + t] = sg;
    }
}

__global__ __launch_bounds__(256) void pose_kernel(
    const float* __restrict__ z, const float* __restrict__ Wp, const float* __restrict__ bp,
    float* __restrict__ pose_out)
{
    __shared__ __align__(16) float As[64 * 36];
    __shared__ __align__(16) float Bs[32 * 128];
    int m0 = blockIdx.x * 64;
    int r  = blockIdx.y;
    int n0 = r * DP;
    int t  = threadIdx.x;
    int rg = t >> 5;
    int cg = t & 31;
    float acc[8][4] = {};
    for (int kt = 0; kt < DIN; kt += 32) {
#pragma unroll
        for (int q = 0; q < 2; ++q) {
            int s = t * 2 + q;
            int row = s >> 3, k4 = s & 7;
            float4 v = *(const float4*)(z + (size_t)(m0 + row) * DIN + kt + k4 * 4);
            *(float4*)(As + row * 36 + k4 * 4) = v;
        }
#pragma unroll
        for (int q = 0; q < 4; ++q) {
            int s = t + 256 * q;
            int row = s >> 5, c4 = s & 31;
            float4 v = *(const float4*)(Wp + (size_t)(kt + row) * (RR * DP) + n0 + c4 * 4);
            *(float4*)(Bs + row * 128 + c4 * 4) = v;
        }
        __syncthreads();
#pragma unroll
        for (int kk = 0; kk < 32; ++kk) {
            float4 bv = *(const float4*)(Bs + kk * 128 + cg * 4);
#pragma unroll
            for (int j = 0; j < 8; ++j) {
                float a = As[(rg * 8 + j) * 36 + kk];
                acc[j][0] += a * bv.x; acc[j][1] += a * bv.y;
                acc[j][2] += a * bv.z; acc[j][3] += a * bv.w;
            }
        }
        __syncthreads();
    }
    float bi0 = bp[n0 + cg * 4], bi1 = bp[n0 + cg * 4 + 1];
    float bi2 = bp[n0 + cg * 4 + 2], bi3 = bp[n0 + cg * 4 + 3];
#pragma unroll
    for (int j = 0; j < 8; ++j) {
        float x0 = acc[j][0] + bi0, x1 = acc[j][1] + bi1;
        float x2 = acc[j][2] + bi2, x3 = acc[j][3] + bi3;
        float ns = x0 * x0 + x1 * x1 + x2 * x2 + x3 * x3;
        for (int off = 1; off < 32; off <<= 1) ns += __shfl_xor(ns, off);
        float factor = (ns / fmaxf(1.0f + ns, 1e-6f)) / (sqrtf(ns) + 1e-6f);
        int row = m0 + rg * 8 + j;
        float4 o = make_float4(x0 * factor, x1 * factor, x2 * factor, x3 * factor);
        *(float4*)(pose_out + ((size_t)row * RR + r) * DP + cg * 4) = o;
    }
}

__global__ __launch_bounds__(256) void votes_kernel(
    const float* __restrict__ pose, const float* __restrict__ wc,
    float* __restrict__ u_out)
{
    __shared__ float As[64 * 129];
    __shared__ __align__(16) float Bs[64 * 80];
    int m0 = blockIdx.x * 64;
    int r  = blockIdx.y;
    int n0 = blockIdx.z * 80;
    int t  = threadIdx.x;
    const size_t wbase = (size_t)r * DP * KH;
#pragma unroll
    for (int q = 0; q < 8; ++q) {
        int s = t + 256 * q;
        int row = s >> 5, d4 = s & 31;
        float4 v = *(const float4*)(pose + ((size_t)(m0 + row) * RR + r) * DP + d4 * 4);
        As[row * 129 + d4 * 4 + 0] = v.x;
        As[row * 129 + d4 * 4 + 1] = v.y;
        As[row * 129 + d4 * 4 + 2] = v.z;
        As[row * 129 + d4 * 4 + 3] = v.w;
    }
    int m4 = t >> 4, n5 = t & 15;
    float acc[4][5];
#pragma unroll
    for (int i = 0; i < 4; ++i)
#pragma unroll
        for (int j = 0; j < 5; ++j) acc[i][j] = 0.f;
    for (int kt = 0; kt < DP; kt += 64) {
        __syncthreads();
#pragma unroll
        for (int q = 0; q < 5; ++q) {
            int s = t + 256 * q;
            int d = s / 20, c4 = s % 20;
            float4 v = *(const float4*)(wc + wbase + (size_t)(kt + d) * KH + n0 + c4 * 4);
            *(float4*)(Bs + d * 80 + c4 * 4) = v;
        }
        __syncthreads();
#pragma unroll 4
        for (int dd = 0; dd < 64; ++dd) {
            int d = kt + dd;
            float b_[5];
#pragma unroll
            for (int j = 0; j < 5; ++j) b_[j] = Bs[dd * 80 + n5 * 5 + j];
#pragma unroll
            for (int i = 0; i < 4; ++i) {
                float a = As[(m4 * 4 + i) * 129 + d];
#pragma unroll
                for (int j = 0; j < 5; ++j) acc[i][j] += a * b_[j];
            }
        }
    }
#pragma unroll
    for (int i = 0; i < 4; ++i) {
        int row = m0 + m4 * 4 + i;
        size_t base = ((size_t)row * RR + r) * KH + n0 + n5 * 5;
#pragma unroll
        for (int j = 0; j < 5; ++j) u_out[base + j] = acc[i][j];
    }
}

__global__ __launch_bounds__(256) void head_kernel(
    const float* __restrict__ ce, const float* __restrict__ g, const float* __restrict__ bb,
    const float* __restrict__ W1, const float* __restrict__ b1,
    const float* __restrict__ W2, const float* __restrict__ b2,
    float* __restrict__ logits)
{
    __shared__ __align__(16) float Y[64 * HD];
    __shared__ float Wc[HD * 64];
    __shared__ float Lg[64];
    int row0 = blockIdx.x * 64;
    int t = threadIdx.x;
    for (int s = t; s < 64 * HD; s += 256) Y[s] = ce[(size_t)row0 * HD + s];
    __syncthreads();
    if (t < 64) {
        float m = 0.f;
        for (int i = 0; i < HD; ++i) m += Y[t * HD + i];
        m *= (1.0f / HD);
        float v = 0.f;
        for (int i = 0; i < HD; ++i) { float d = Y[t * HD + i] - m; v += d * d; }
        v *= (1.0f / HD);
        float rstd = rsqrtf(v + 1e-5f);
        for (int i = 0; i < HD; ++i) Y[t * HD + i] = (Y[t * HD + i] - m) * rstd * g[i] + bb[i];
    }
    int rg = t >> 4;
    int cg = t & 15;
    float accRow[4] = {0.f, 0.f, 0.f, 0.f};
    for (int c0 = 0; c0 < H4; c0 += 64) {
        __syncthreads();
        for (int s = t; s < HD * 64; s += 256) {
            int i = s >> 6, c = s & 63;
            Wc[i * 64 + c] = W1[(size_t)i * H4 + c0 + c];
        }
        __syncthreads();
        float b1v[4], w2v[4];
#pragma unroll
        for (int c = 0; c < 4; ++c) { b1v[c] = b1[c0 + cg * 4 + c]; w2v[c] = W2[c0 + cg * 4 + c]; }
        float s_[4][4];
#pragma unroll
        for (int rr = 0; rr < 4; ++rr)
#pragma unroll
            for (int c = 0; c < 4; ++c) s_[rr][c] = b1v[c];
        for (int i4 = 0; i4 < HD / 4; ++i4) {
            float4 y4[4];
#pragma unroll
            for (int rr = 0; rr < 4; ++rr)
                y4[rr] = *(const float4*)(Y + (rg * 4 + rr) * HD + i4 * 4);
#pragma unroll
            for (int is = 0; is < 4; ++is) {
                float w_[4];
#pragma unroll
                for (int c = 0; c < 4; ++c) w_[c] = Wc[(i4 * 4 + is) * 64 + cg * 4 + c];
#pragma unroll
                for (int rr = 0; rr < 4; ++rr) {
                    float yv = (is == 0) ? y4[rr].x : (is == 1) ? y4[rr].y : (is == 2) ? y4[rr].z : y4[rr].w;
#pragma unroll
                    for (int c = 0; c < 4; ++c) s_[rr][c] += yv * w_[c];
                }
            }
        }
#pragma unroll
        for (int rr = 0; rr < 4; ++rr) {
#pragma unroll
            for (int c = 0; c < 4; ++c) {
                float x = s_[rr][c];
                float ge = 0.5f * x * (1.0f + erff(x * 0.70710678118654752440f));
                accRow[rr] += ge * w2v[c];
            }
        }
    }
#pragma unroll
    for (int rr = 0; rr < 4; ++rr) {
        float v = accRow[rr];
        v += __shfl_xor(v, 1); v += __shfl_xor(v, 2);
        v += __shfl_xor(v, 4); v += __shfl_xor(v, 8);
        if (cg == 0) Lg[rg * 4 + rr] = v;
    }
    __syncthreads();
    if (t < 64) logits[row0 + t] = Lg[t] + b2[0];
}

// ---------------------------------------------------------------------------
extern "C" void kernel_launch(void* const* d_in, const int* in_sizes, int n_in,
                              void* d_out, int out_size, void* d_ws, size_t ws_size,
                              hipStream_t stream) {
    const float* z    = (const float*)d_in[0];
    const float* Wp   = (const float*)d_in[1];
    const float* bp   = (const float*)d_in[2];
    const float* lnag = (const float*)d_in[3];
    const float* lnab = (const float*)d_in[4];
    const float* Wa   = (const float*)d_in[5];
    const float* ba   = (const float*)d_in[6];
    const float* wc   = (const float*)d_in[7];
    const float* lncg = (const float*)d_in[8];
    const float* lncb = (const float*)d_in[9];
    const float* beta = (const float*)d_in[10];
    const float* lnhg = (const float*)d_in[11];
    const float* lnhb = (const float*)d_in[12];
    const float* W1   = (const float*)d_in[13];
    const float* b1   = (const float*)d_in[14];
    const float* W2   = (const float*)d_in[15];
    const float* b2   = (const float*)d_in[16];

    float* out = (float*)d_out;
    float* o_logits = out;
    float* o_ce   = o_logits + (size_t)BB * KK;
    float* o_cp   = o_ce   + (size_t)BB * KK * HD;
    float* o_ca   = o_cp   + (size_t)BB * KK * DC;
    float* o_q    = o_ca   + (size_t)BB * KK;
    float* o_pose = o_q    + (size_t)BB * RK;
    float* o_act  = o_pose + (size_t)BB * RR * DP;
    float* o_rce  = o_act  + (size_t)BB * RR;

    // ws element counts
    const size_t WPT_ELE  = (size_t)(RR * DP) * DIN;    // 1,835,008 ushort
    const size_t WCT_ELE  = (size_t)RR * KH * DP;       // 358,400 ushort
    const size_t W1TP_ELE = (size_t)H4 * 128;           // 57,344 ushort (padded)
    const size_t W1T_ELE  = (size_t)H4 * HD;            // 50,176 ushort
    const size_t STATS_B  = (size_t)BB * KK * sizeof(float2);   // 819,200 B
    const size_t WG_B     = (size_t)DIN * RR * sizeof(float);   // 57,344 B
    const size_t GC_B     = 64;

    // full layout: [WpT][wcT][W1Tp][stats][Wg][GC]
    unsigned short* WpT  = (unsigned short*)d_ws;
    unsigned short* wcT  = WpT + WPT_ELE;
    unsigned short* W1Tp = wcT + WCT_ELE;
    float2* stats = (float2*)((char*)(W1Tp + W1TP_ELE));
    float*  Wg_f  = (float*)((char*)stats + STATS_B);
    float*  GC_f  = (float*)((char*)Wg_f + WG_B);
    const size_t WS_FULL = (WPT_ELE + WCT_ELE + W1TP_ELE) * 2 + STATS_B + WG_B + GC_B;

    // mid layout: [WpT][wcT][W1T][Wg][GC]
    unsigned short* W1Tm = wcT + WCT_ELE;
    float* Wg_m = (float*)((char*)(W1Tm + W1T_ELE));
    float* GC_m = (float*)((char*)Wg_m + WG_B);
    const size_t WS_MID = (WPT_ELE + WCT_ELE + W1T_ELE) * 2 + WG_B + GC_B;

    if (ws_size >= WS_FULL) {
        hipLaunchKernelGGL(prep_act_kernel, dim3(1), dim3(256), 0, stream, lnag, lnab, Wa, Wg_f, GC_f);
        hipLaunchKernelGGL(act_v2, dim3(BB / 8), dim3(256), 0, stream, z, Wg_f, GC_f, ba, o_act);
        hipLaunchKernelGGL(transpose_cvt_kernel, dim3(DIN / 64, (RR * DP) / 64, 1), dim3(256), 0, stream,
                           Wp, WpT, DIN, DIN, RR * DP);
        hipLaunchKernelGGL(transpose_cvt_kernel, dim3(2, 7, 1), dim3(256), 0, stream,
                           W1, W1Tp, HD, 128, H4);
        hipLaunchKernelGGL(transpose_cvt_kernel, dim3(2, 7, RR), dim3(256), 0, stream,
                           wc, wcT, DP, DP, KH);
        hipLaunchKernelGGL(pose64, dim3(BB / 64, RR), dim3(256), 0, stream, z, WpT, bp, o_pose);
        hipLaunchKernelGGL(votes_mfma, dim3(BB / 128, RR, 5), dim3(256), 0, stream, o_pose, wcT, o_rce);
        hipLaunchKernelGGL(routing_kernel, dim3(BB), dim3(64), 0, stream,
                           o_rce, o_act, lncg, lncb, beta, o_q, o_cp, o_ca, o_rce, o_ce, stats);
        hipLaunchKernelGGL(head_v3, dim3(BB * KK / 128), dim3(256), 0, stream,
                           o_ce, stats, lnhg, lnhb, W1Tp, b1, W2, b2, o_logits);
    } else if (ws_size >= WS_MID) {
        hipLaunchKernelGGL(prep_act_kernel, dim3(1), dim3(256), 0, stream, lnag, lnab, Wa, Wg_m, GC_m);
        hipLaunchKernelGGL(act_v2, dim3(BB / 8), dim3(256), 0, stream, z, Wg_m, GC_m, ba, o_act);
        hipLaunchKernelGGL(transpose_cvt_kernel, dim3(DIN / 64, (RR * DP) / 64, 1), dim3(256), 0, stream,
                           Wp, WpT, DIN, DIN, RR * DP);
        hipLaunchKernelGGL(transpose_cvt_kernel, dim3(2, 7, 1), dim3(256), 0, stream,
                           W1, W1Tm, HD, HD, H4);
        hipLaunchKernelGGL(transpose_cvt_kernel, dim3(2, 7, RR), dim3(256), 0, stream,
                           wc, wcT, DP, DP, KH);
        hipLaunchKernelGGL(pose64, dim3(BB / 64, RR), dim3(256), 0, stream, z, WpT, bp, o_pose);
        hipLaunchKernelGGL(votes_mfma, dim3(BB / 128, RR, 5), dim3(256), 0, stream, o_pose, wcT, o_rce);
        hipLaunchKernelGGL(routing_kernel, dim3(BB), dim3(64), 0, stream,
                           o_rce, o_act, lncg, lncb, beta, o_q, o_cp, o_ca, o_rce, o_ce, (float2*)nullptr);
        hipLaunchKernelGGL(head_mfma, dim3(BB * KK / 128), dim3(256), 0, stream,
                           o_ce, lnhg, lnhb, W1Tm, b1, W2, b2, o_logits);
    } else {
        hipLaunchKernelGGL(act_kernel, dim3(BB), dim3(256), 0, stream, z, lnag, lnab, Wa, ba, o_act);
        hipLaunchKernelGGL(pose_kernel, dim3(BB / 64, RR), dim3(256), 0, stream, z, Wp, bp, o_pose);
        hipLaunchKernelGGL(votes_kernel, dim3(BB / 64, RR, 5), dim3(256), 0, stream, o_pose, wc, o_rce);
        hipLaunchKernelGGL(routing_kernel, dim3(BB), dim3(64), 0, stream,
                           o_rce, o_act, lncg, lncb, beta, o_q, o_cp, o_ca, o_rce, o_ce, (float2*)nullptr);
        hipLaunchKernelGGL(head_kernel, dim3(BB * KK / 64), dim3(256), 0, stream,
                           o_ce, lnhg, lnhb, W1, b1, W2, b2, o_logits);
    }
}